// Round 7
// baseline (241.799 us; speedup 1.0000x reference)
//
#include <hip/hip_runtime.h>
#include <math.h>

// InnerPatchSoftShiftTriple — v8: one-shot 8-wave blocks, stencil-addressed
// non-tripled K-slab, fragment-ordered U in LDS, PV B from global [ch][k'].
//
// s[l,k] = sum_{bb,aa,c} lat[c][R(l,bb,aa)] * knorm[c][R(k,bb,aa)]
// R(m,bb,aa) = Tinv(T(m)+bb-1)+(aa-1), valid iff intermediate/final in [0,L)
// T(m)=Tinv(m)=((m&63)<<6)|(m>>6).  k swept as k=Tinv(k'), k' contiguous.
// Column tap for k'-col at (bb,aa): j=k'+bb-1 (valid in [0,L)), q=Tinv(j)+aa-1
// (valid in [0,L)), data at knxg row t2=T(q) (knxg[r] = knorm[Tinv(r-66)],
// pre-XOR-swizzled by (t2&7)<<4). t2 = j+64(aa-1) except h-boundary wraps,
// which occur only for ks in {0,7} and are staged into an 8KB LDS patch.

#define L 4096
typedef unsigned int   u32;
typedef unsigned short u16;
typedef short  short8 __attribute__((ext_vector_type(8)));
typedef float  f32x16 __attribute__((ext_vector_type(16)));

#define MFMA32(a,b,c) __builtin_amdgcn_mfma_f32_32x32x16_bf16((a),(b),(c),0,0,0)

__device__ __forceinline__ u16 f2bf(float f){ u32 u=__float_as_uint(f); return (u16)((u+0x7FFFu+((u>>16)&1u))>>16); }
__device__ __forceinline__ u32 pack2(float a, float b){ return (u32)f2bf(a) | ((u32)f2bf(b)<<16); }
__device__ __forceinline__ void lds_async16(void* lds, const void* g){
  __builtin_amdgcn_global_load_lds((const __attribute__((address_space(1))) u32*)g,
                                   (__attribute__((address_space(3))) u32*)lds, 16, 0, 0);
}

// ---- ws layout (bytes) ----
#define OFF_LATB  0u         // u16[2][4096][64] raw latter (transposed, row-major l)
#define OFF_FORKP 1048576u   // u16[2][64][4096] former, ch-major, k'-ordered cols
#define OFF_KNXG  2097152u   // 2 x 4236 rows x 128 B  (66-row guards both ends + pad)
#define KNXG_BB   542208u    // 4236*128
#define OFF_FBITS 3211264u
#define OFF_ROWS  3211776u
#define OFF_CNT   3228160u
#define OFF_DONE  3228416u
#define OFF_PART  3229440u   // [2][64][8] x (32 rows x 144 B) -> end 7,948,032

// ---- k_flash LDS layout ----
#define SLAB_O  0
#define POFF    82432        // patch 64 x 128
#define ZOFF    90624        // zero row 128
#define UOFF    90752        // ub: 36 frags x 64 lanes x 16 B
#define PSOFF   127616       // p_s: 8 waves x 32 rows x 136 B
#define RLOFF   162432
#define SMEM_SZ 162688

// ================= fused pre-pass =================
__global__ void k_pre1(const float4* __restrict__ x4, float4* __restrict__ out4,
                       const float* __restrict__ x, const float* __restrict__ mask,
                       u16* __restrict__ latb, u16* __restrict__ forkp,
                       char* __restrict__ knxg, int* __restrict__ rows,
                       int* __restrict__ cnt, u32* __restrict__ fbits,
                       u32* __restrict__ done)
{
    __shared__ float tl[64*65];
    __shared__ int lcnt;
    __shared__ u32 lb[128];
    const int blk = blockIdx.x, t = threadIdx.x;
    if (blk < 1536) {                       // passthrough copy + zero shift
        int i = blk*256 + t;
        if (i < 262144) { int b=i>>17, j=i&131071; out4[b*196608+j] = x4[b*131072+j]; }
        else { int z=i-262144; int b=z>>16, j=z&65535; out4[b*196608+131072+j] = make_float4(0.f,0.f,0.f,0.f); }
    } else if (blk < 1568) {                // norm + latb + knxg (swizzled scatter)
        int tid = (blk-1536)*256+t; int b = tid>>12, l = tid&4095;
        const float* xb = x + (size_t)b*524288;
        float v[64]; float ss=0.f;
        #pragma unroll
        for (int c=0;c<64;++c){ v[c]=xb[(64+c)*4096+l]; ss+=v[c]*v[c]; }
        float inv = 1.f/fmaxf(sqrtf(ss),1e-4f);
        u16* lr = latb + (size_t)(b*4096+l)*64;
        #pragma unroll
        for (int c8=0;c8<8;++c8){
            uint4 pq = make_uint4(pack2(v[c8*8],v[c8*8+1]),pack2(v[c8*8+2],v[c8*8+3]),
                                  pack2(v[c8*8+4],v[c8*8+5]),pack2(v[c8*8+6],v[c8*8+7]));
            *(uint4*)(lr + c8*8) = pq;
        }
        int t2 = ((l&63)<<6)|(l>>6);
        char* dst = knxg + (size_t)b*KNXG_BB + (size_t)(t2+66)*128;
        int key = (t2&7)<<4;
        #pragma unroll
        for (int c8=0;c8<8;++c8){
            uint4 pq = make_uint4(pack2(v[c8*8]*inv,v[c8*8+1]*inv),pack2(v[c8*8+2]*inv,v[c8*8+3]*inv),
                                  pack2(v[c8*8+4]*inv,v[c8*8+5]*inv),pack2(v[c8*8+6]*inv,v[c8*8+7]*inv));
            *(uint4*)(dst + ((c8*16)^key)) = pq;
        }
    } else if (blk < 1696) {                // forkp: [ch][k'] via LDS tile transpose
        int blk2 = blk-1568; int b = blk2>>6, ch = blk2&63;
        const float* in = x + (size_t)b*524288 + (size_t)ch*4096;
        #pragma unroll
        for (int i=0;i<16;++i){ int idx = t+256*i; tl[(idx&63)*65 + (idx>>6)] = in[idx]; }
        __syncthreads();
        u32* orow = (u32*)forkp + (size_t)(b*64+ch)*2048;
        #pragma unroll
        for (int i=0;i<8;++i){
            int j2 = t+256*i; int j = 2*j2;
            float f0 = tl[(j>>6)*65 + (j&63)];
            float f1 = tl[((j+1)>>6)*65 + ((j+1)&63)];
            orow[j2] = pack2(f0,f1);
        }
    } else if (blk < 1698) {                // knxg guard rows zero
        int b = blk-1696;
        char* gB = knxg + (size_t)b*KNXG_BB;
        uint4 z = make_uint4(0,0,0,0);
        #pragma unroll
        for (int i=0;i<5;++i){
            int idx = t+256*i;
            if (idx < 1120){
                int row = (idx<528) ? (idx>>3) : (4162 + ((idx-528)>>3));
                *(uint4*)(gB + (size_t)row*128 + (idx&7)*16) = z;
            }
        }
    } else {                                // compact + fbits + done zero
        if (t==0) lcnt=0;
        if (t<128) lb[t]=0u;
        __syncthreads();
        for (int i=t;i<L;i+=256){
            if (mask[i] > 0.5f){
                int p = atomicAdd(&lcnt,1);
                if (p<2048) rows[p]=i;
                int kp = ((i&63)<<6)|(i>>6);
                atomicOr(&lb[kp>>5], 1u<<(kp&31));
            }
        }
        __syncthreads();
        if (t<128) fbits[t]=lb[t];
        if (t<128) done[t]=0u;
        if (t==0) cnt[0]=min(lcnt,2048);
    }
}

// ================= main flash kernel =================
__global__ __launch_bounds__(512,1)
void k_flash(const u16* __restrict__ latb, const u16* __restrict__ forkp,
             const char* __restrict__ knxg, const u32* __restrict__ fbits,
             const int* __restrict__ rows, const int* __restrict__ cnt,
             char* __restrict__ part, u32* __restrict__ done, float* __restrict__ out)
{
    extern __shared__ char smem[];
    const int t = threadIdx.x;
    // XCD-aware decode: each (ks,b) group of 64 rt-blocks lives on one XCD
    const int lin = blockIdx.x;
    const int xcd = lin&7, qd = lin>>3;
    const int gid = xcd*128 + qd;
    const int ksb = gid>>6, rt = gid&63;
    const int ks = ksb>>1, b = ksb&1;
    const int count = cnt[0];
    const int base = rt*32;
    if (base >= count) return;
    const int nact = min(32, count-base);
    int* rl_s = (int*)(smem + RLOFF);
    if (t < 32) rl_s[t] = rows[base + min(t, nact-1)];
    if (t < 8) *(uint4*)(smem + ZOFF + t*16) = make_uint4(0,0,0,0);
    __syncthreads();

    const int l = t&63, w = t>>6, li = l&31, hi = l>>5;
    const int k0 = ks*512, wOff = w*64;
    const int plo = (ks==0) ? 4031 : 1;
    const char* slabsrc = knxg + (size_t)b*KNXG_BB + (size_t)k0*128;

    // ---- stage slab: 643 rows x 128 B, linear global_load_lds ----
    #pragma unroll
    for (int i=0;i<11;++i){
        int idx = w + 8*i;
        if (idx < 80 || (idx == 80 && l < 24))
            lds_async16(smem + SLAB_O + idx*1024, slabsrc + idx*1024 + l*16);
    }
    if (ks==0 || ks==7){
        const char* psrc = knxg + (size_t)b*KNXG_BB + (size_t)(plo+66)*128;
        lds_async16(smem + POFF + w*1024, psrc + w*1024 + l*16);
    }
    // ---- stage ub: fragment-ordered U (36 frags x 64 lanes x 16B) ----
    {
        const u16* latbb = latb + (size_t)b*262144;
        int gl = rl_s[li];
        int tl0 = ((gl&63)<<6)|(gl>>6);
        #pragma unroll
        for (int rep=0;rep<5;++rep){
            int f = w + 8*rep;
            if (f < 36){
                int tap = f>>2, Ks = f&3;
                int bb = tap/3, aa = tap - 3*bb;
                int mp = tl0 + bb - 1;
                short8 val = {0,0,0,0,0,0,0,0};
                if (mp>=0 && mp<L){
                    int qq = (((mp&63)<<6)|(mp>>6)) + aa - 1;
                    if (qq>=0 && qq<L)
                        val = *(const short8*)(latbb + (size_t)qq*64 + Ks*16 + hi*8);
                }
                *(short8*)(smem + UOFF + f*1024 + l*16) = val;
            }
        }
    }
    // ---- per-lane slab addresses (once): pk = rowbase | xor-key ----
    int pkA[2][9];
    #pragma unroll
    for (int Mt=0; Mt<2; ++Mt){
        #pragma unroll
        for (int tap=0; tap<9; ++tap){
            const int bb = tap/3, aa = tap - 3*(tap/3);
            int j = k0 + wOff + Mt*32 + li + bb - 1;
            int pk = ZOFF;
            if ((u32)j < (u32)L){
                int qq = (j&63)*64 + (j>>6) + aa - 1;
                if ((u32)qq < (u32)L){
                    int t2 = ((qq&63)<<6) | (qq>>6);
                    int key = (t2&7)<<4;
                    int s = t2 - k0 + 66;
                    if ((u32)s < 643u) pk = SLAB_O + s*128 + key;
                    else               pk = POFF + (t2 - plo)*128 + key;
                }
            }
            pkA[Mt][tap] = pk;
        }
    }

    asm volatile("s_waitcnt vmcnt(0)" ::: "memory");
    __syncthreads();

    // ---- score: 72 MFMA, A from slab/patch, B from ub ----
    f32x16 sc0, sc1;
    #pragma unroll
    for (int r=0;r<16;++r){ sc0[r]=0.f; sc1[r]=0.f; }
    const char* ubp = smem + UOFF + l*16;
    const int X0 = hi*16;
    __builtin_amdgcn_s_setprio(1);
    #pragma unroll
    for (int tap=0; tap<9; ++tap){
        const int r0 = pkA[0][tap] & ~127, y0 = pkA[0][tap] & 127;
        const int r1 = pkA[1][tap] & ~127, y1 = pkA[1][tap] & 127;
        #pragma unroll
        for (int Ks=0; Ks<4; ++Ks){
            short8 bu = *(const short8*)(ubp + (tap*4+Ks)*1024);
            short8 a0 = *(const short8*)(smem + r0 + ((X0 + Ks*32) ^ y0));
            short8 a1 = *(const short8*)(smem + r1 + ((X0 + Ks*32) ^ y1));
            sc0 = MFMA32(a0, bu, sc0);
            sc1 = MFMA32(a1, bu, sc1);
        }
    }
    __builtin_amdgcn_s_setprio(0);

    // ---- PV B prefetch from forkp[ch][k'] (issue early, consume post-softmax) ----
    const u16* fKb = forkp + (size_t)b*262144;
    short8 fb0[4], fb1[4];
    #pragma unroll
    for (int Ks=0;Ks<4;++Ks){
        fb0[Ks] = *(const short8*)(fKb + (size_t)li*4096      + k0 + wOff + Ks*16 + hi*8);
        fb1[Ks] = *(const short8*)(fKb + (size_t)(32+li)*4096 + k0 + wOff + Ks*16 + hi*8);
    }

    // ---- mask + softmax (row = lane li; cols in regs) ----
    const int fw = (k0 + wOff) >> 5;
    const u32 bits0 = fbits[fw], bits1 = fbits[fw+1];
    float mx = -INFINITY;
    #pragma unroll
    for (int r=0;r<16;++r){
        int kl = (r&3) + 8*(r>>2) + 4*hi;
        float s0 = sc0[r]; if ((bits0>>kl)&1u) s0 = -INFINITY;
        float s1 = sc1[r]; if ((bits1>>kl)&1u) s1 = -INFINITY;
        sc0[r]=s0; sc1[r]=s1;
        mx = fmaxf(mx, fmaxf(s0,s1));
    }
    mx = fmaxf(mx, __shfl_xor(mx, 32, 64));
    float sum = 0.f;
    u32 pw0[8], pw1[8];
    if (mx > -INFINITY){
        #pragma unroll
        for (int rq=0;rq<8;++rq){
            float p00 = __expf(sc0[2*rq]-mx), p01 = __expf(sc0[2*rq+1]-mx);
            float p10 = __expf(sc1[2*rq]-mx), p11 = __expf(sc1[2*rq+1]-mx);
            sum += (p00+p01)+(p10+p11);
            pw0[rq] = pack2(p00,p01);
            pw1[rq] = pack2(p10,p11);
        }
    } else {
        #pragma unroll
        for (int rq=0;rq<8;++rq){ pw0[rq]=0u; pw1[rq]=0u; }
    }
    sum += __shfl_xor(sum, 32, 64);
    char* pswr = smem + PSOFF + w*4352 + li*136;
    #pragma unroll
    for (int rq=0;rq<8;++rq){
        int r = 2*rq;
        int kl = (r&3) + 8*(r>>2) + 4*hi;
        *(u32*)(pswr + kl*2)      = pw0[rq];
        *(u32*)(pswr + 64 + kl*2) = pw1[rq];
    }

    // ---- PV: A from p_s, B from prefetched fb ----
    f32x16 ac0, ac1;
    #pragma unroll
    for (int r=0;r<16;++r){ ac0[r]=0.f; ac1[r]=0.f; }
    #pragma unroll
    for (int Ks=0;Ks<4;++Ks){
        short8 pa = *(const short8*)(pswr + Ks*32 + X0);
        ac0 = MFMA32(pa, fb0[Ks], ac0);
        ac1 = MFMA32(pa, fb1[Ks], ac1);
    }

    // ---- merge 8 waves via um (aliases slab) ----
    __syncthreads();
    float* um = (float*)smem;   // [8][32][66]
    if (hi==0){ um[(w*32+li)*66+0] = mx; um[(w*32+li)*66+1] = sum; }
    #pragma unroll
    for (int r=0;r<16;++r){
        int kl = (r&3)+8*(r>>2)+4*hi;
        um[(w*32+kl)*66 + 2 + li]      = ac0[r];
        um[(w*32+kl)*66 + 2 + 32 + li] = ac1[r];
    }
    __syncthreads();
    {
        int row = t>>4, cq = t&15, ch4 = cq*4;
        float M = -INFINITY; float m8[8], s8[8];
        #pragma unroll
        for (int wv=0;wv<8;++wv){ m8[wv]=um[(wv*32+row)*66]; s8[wv]=um[(wv*32+row)*66+1]; M=fmaxf(M,m8[wv]); }
        float S=0.f; float a4[4]={0.f,0.f,0.f,0.f};
        if (M > -INFINITY){
            #pragma unroll
            for (int wv=0;wv<8;++wv){
                float e = __expf(m8[wv]-M);
                S += s8[wv]*e;
                #pragma unroll
                for (int i=0;i<4;++i) a4[i] += e * um[(wv*32+row)*66 + 2 + ch4 + i];
            }
        }
        char* rec = part + ((size_t)((b*64+rt)*8 + ks))*4608 + row*144;
        if (cq==0){ *(float*)rec = M; *(float*)(rec+4) = S; }
        uint2 hw; hw.x = pack2(a4[0],a4[1]); hw.y = pack2(a4[2],a4[3]);
        *(uint2*)(rec + 16 + ch4*2) = hw;
    }

    // ---- fan-in: last of 8 ks blocks writes final shift ----
    __threadfence();
    __syncthreads();
    if (t==0) rl_s[0] = (atomicAdd(&done[b*64+rt],1u) == 7u) ? 1 : 0;
    __syncthreads();
    if (!rl_s[0]) return;
    __threadfence();
    {
        int row = t>>4, cq = t&15, ch4 = cq*4;
        int slot = base + row;
        if (slot < count){
            int lr2 = rows[slot];
            const char* pbp = part + ((size_t)((b*64+rt)*8))*4608 + row*144;
            float M=-INFINITY; float m8[8], s8[8];
            #pragma unroll
            for (int k=0;k<8;++k){ m8[k]=*(const float*)(pbp+k*4608); s8[k]=*(const float*)(pbp+k*4608+4); M=fmaxf(M,m8[k]); }
            if (M > -INFINITY){
                float S=0.f; float a4[4]={0.f,0.f,0.f,0.f};
                #pragma unroll
                for (int k=0;k<8;++k){
                    float e = __expf(m8[k]-M);
                    S += s8[k]*e;
                    uint2 hv = *(const uint2*)(pbp + k*4608 + 16 + ch4*2);
                    a4[0] += e*__uint_as_float((hv.x&0xffffu)<<16);
                    a4[1] += e*__uint_as_float(hv.x & 0xffff0000u);
                    a4[2] += e*__uint_as_float((hv.y&0xffffu)<<16);
                    a4[3] += e*__uint_as_float(hv.y & 0xffff0000u);
                }
                float invS = (S>0.f) ? 1.f/S : 0.f;
                float* ob = out + (size_t)b*786432 + 524288 + lr2;
                #pragma unroll
                for (int i=0;i<4;++i) ob[(size_t)(ch4+i)*4096] = a4[i]*invS;
            }
        }
    }
}

extern "C" void kernel_launch(void* const* d_in, const int* in_sizes, int n_in,
                              void* d_out, int out_size, void* d_ws, size_t ws_size,
                              hipStream_t stream)
{
    const float* x    = (const float*)d_in[0];
    const float* mask = (const float*)d_in[1];
    float* out = (float*)d_out;
    char* ws = (char*)d_ws;

    u16* latb  = (u16*)(ws + OFF_LATB);
    u16* forkp = (u16*)(ws + OFF_FORKP);
    char* knxg = ws + OFF_KNXG;
    u32* fbits = (u32*)(ws + OFF_FBITS);
    int* rows  = (int*)(ws + OFF_ROWS);
    int* cnt   = (int*)(ws + OFF_CNT);
    u32* done  = (u32*)(ws + OFF_DONE);
    char* part = ws + OFF_PART;

    k_pre1<<<1699, 256, 0, stream>>>((const float4*)x, (float4*)out, x, mask,
                                     latb, forkp, knxg, rows, cnt, fbits, done);
    hipFuncSetAttribute((const void*)k_flash, hipFuncAttributeMaxDynamicSharedMemorySize, SMEM_SZ);
    k_flash<<<1024, 512, SMEM_SZ, stream>>>(latb, forkp, knxg, fbits, rows, cnt, part, done, out);
}